// Round 1
// baseline (638.257 us; speedup 1.0000x reference)
//
#include <hip/hip_runtime.h>

#define NN 8192
#define CC 512

typedef __bf16 bhalf;
typedef bhalf bhalf8 __attribute__((ext_vector_type(8)));
typedef bhalf bhalf4 __attribute__((ext_vector_type(4)));
typedef float f32x4 __attribute__((ext_vector_type(4)));

// ---------------------------------------------------------------------------
// Pass 1: degree sums over A (one full read), optionally emitting A as bf16.
// Tile: 64 rows x 1024 cols per block. grid = (8192/1024, 8192/64) = (8,128).
// Row sums: per-thread partial (4 cols) -> LDS [64][256] -> 4-thread reduce ->
// atomicAdd. Col sums: per-thread register accumulate over 64 rows -> atomicAdd.
// ---------------------------------------------------------------------------
template <int WRITE_BF16>
__global__ __launch_bounds__(256) void k_degrees(const float* __restrict__ A,
                                                 float* __restrict__ row_deg,
                                                 float* __restrict__ col_deg,
                                                 bhalf* __restrict__ Abf) {
    __shared__ float rp[64 * 256];  // 64 KB
    const int t  = threadIdx.x;
    const int c  = blockIdx.x * 1024 + t * 4;
    const int r0 = blockIdx.y * 64;
    float c0 = 0.f, c1 = 0.f, c2 = 0.f, c3 = 0.f;
#pragma unroll 8
    for (int r = 0; r < 64; ++r) {
        const float4 v = *(const float4*)(A + (size_t)(r0 + r) * NN + c);
        c0 += v.x; c1 += v.y; c2 += v.z; c3 += v.w;
        rp[r * 256 + t] = (v.x + v.y) + (v.z + v.w);
        if (WRITE_BF16) {
            bhalf4 o;
            o[0] = (bhalf)v.x; o[1] = (bhalf)v.y; o[2] = (bhalf)v.z; o[3] = (bhalf)v.w;
            *(bhalf4*)(Abf + (size_t)(r0 + r) * NN + c) = o;
        }
    }
    atomicAdd(&col_deg[c + 0], c0);
    atomicAdd(&col_deg[c + 1], c1);
    atomicAdd(&col_deg[c + 2], c2);
    atomicAdd(&col_deg[c + 3], c3);
    __syncthreads();
    // 4 threads per row; staggered LDS reads (bank = (i+t)%32, 2-way max -> free)
    const int r = t >> 2;
    const int g = (t & 3) * 64;
    float s = 0.f;
#pragma unroll 8
    for (int i = 0; i < 64; ++i) s += rp[r * 256 + g + ((i + t) & 63)];
    atomicAdd(&row_deg[r0 + r], s);
}

// ---------------------------------------------------------------------------
// Pass 2: rsqrt of degrees + zero flag. 8192 elems.
// ---------------------------------------------------------------------------
__global__ __launch_bounds__(256) void k_finalize(const float* __restrict__ rd,
                                                  const float* __restrict__ cd,
                                                  float* __restrict__ rsr,
                                                  float* __restrict__ rsc,
                                                  int* __restrict__ flag) {
    const int i = blockIdx.x * 256 + threadIdx.x;
    const float r = rd[i], c = cd[i];
    rsr[i] = (r > 0.f) ? rsqrtf(r) : 0.f;
    rsc[i] = (c > 0.f) ? rsqrtf(c) : 0.f;
    if (r == 0.f || c == 0.f) atomicExch(flag, 1);
}

// ---------------------------------------------------------------------------
// Pass 3: ht[n][k] = relu( sum_c feat[k][c]*W[n][c] + b[n] ) * rsqrt_col[k]
// stored bf16, K-contiguous (transposed) so GEMM2 B-frags are contiguous.
// 128x128 tile, BK=32, 16x16x32 bf16 MFMA, 4 waves in 2x2. grid=(4,64).
// ---------------------------------------------------------------------------
__global__ __launch_bounds__(256, 2) void k_h(const float* __restrict__ feat,
                                              const float* __restrict__ W,
                                              const float* __restrict__ bias,
                                              const float* __restrict__ rsc,
                                              bhalf* __restrict__ ht) {
    constexpr int LDA = 40;  // shorts per LDS row (+8 pad: 2-way bank alias max)
    __shared__ __align__(16) bhalf lsA[128 * LDA];
    __shared__ __align__(16) bhalf lsB[128 * LDA];
    const int n0   = blockIdx.x * 128;  // output-feature tile
    const int m0   = blockIdx.y * 128;  // k-row tile
    const int t    = threadIdx.x;
    const int lane = t & 63, wave = t >> 6;
    const int wm = (wave >> 1) * 64, wn = (wave & 1) * 64;
    const int qk = (lane >> 4) * 8, rsel = lane & 15;
    f32x4 acc[4][4];
#pragma unroll
    for (int a = 0; a < 4; ++a)
#pragma unroll
        for (int bq = 0; bq < 4; ++bq)
#pragma unroll
            for (int e = 0; e < 4; ++e) acc[a][bq][e] = 0.f;

    for (int k0 = 0; k0 < CC; k0 += 32) {
        // stage A (features) and B (W rows), fp32 -> bf16
#pragma unroll
        for (int i = 0; i < 4; ++i) {
            const int ch = i * 256 + t;       // 1024 float4 chunks per operand
            const int r = ch >> 3, seg = ch & 7;
            const float4 v = *(const float4*)(feat + (size_t)(m0 + r) * CC + k0 + seg * 4);
            bhalf4 o;
            o[0] = (bhalf)v.x; o[1] = (bhalf)v.y; o[2] = (bhalf)v.z; o[3] = (bhalf)v.w;
            *(bhalf4*)(lsA + r * LDA + seg * 4) = o;
            const float4 w = *(const float4*)(W + (size_t)(n0 + r) * CC + k0 + seg * 4);
            bhalf4 ow;
            ow[0] = (bhalf)w.x; ow[1] = (bhalf)w.y; ow[2] = (bhalf)w.z; ow[3] = (bhalf)w.w;
            *(bhalf4*)(lsB + r * LDA + seg * 4) = ow;
        }
        __syncthreads();
        bhalf8 af[4], bf[4];
#pragma unroll
        for (int x = 0; x < 4; ++x) {
            af[x] = *(const bhalf8*)(lsA + (wm + x * 16 + rsel) * LDA + qk);
            bf[x] = *(const bhalf8*)(lsB + (wn + x * 16 + rsel) * LDA + qk);
        }
#pragma unroll
        for (int mt = 0; mt < 4; ++mt)
#pragma unroll
            for (int nt = 0; nt < 4; ++nt)
                acc[mt][nt] = __builtin_amdgcn_mfma_f32_16x16x32_bf16(af[mt], bf[nt],
                                                                      acc[mt][nt], 0, 0, 0);
        __syncthreads();
    }
    // epilogue: relu(acc+b)*rsc, write transposed bf16 (4 consecutive k per lane)
#pragma unroll
    for (int mt = 0; mt < 4; ++mt) {
        const int kbase = m0 + wm + mt * 16 + (lane >> 4) * 4;
        const float s0 = rsc[kbase + 0], s1 = rsc[kbase + 1];
        const float s2 = rsc[kbase + 2], s3 = rsc[kbase + 3];
#pragma unroll
        for (int nt = 0; nt < 4; ++nt) {
            const int n = n0 + wn + nt * 16 + rsel;
            const float bn = bias[n];
            bhalf4 o;
            o[0] = (bhalf)(fmaxf(acc[mt][nt][0] + bn, 0.f) * s0);
            o[1] = (bhalf)(fmaxf(acc[mt][nt][1] + bn, 0.f) * s1);
            o[2] = (bhalf)(fmaxf(acc[mt][nt][2] + bn, 0.f) * s2);
            o[3] = (bhalf)(fmaxf(acc[mt][nt][3] + bn, 0.f) * s3);
            *(bhalf4*)(ht + (size_t)n * NN + kbase) = o;
        }
    }
}

// ---------------------------------------------------------------------------
// Pass 4: out[i][j] = flag ? feat : rsr[i] * (sum_k A[i][k]*ht[j][k]) + feat
// 128x128 tile, BK=32, K=8192. A from bf16 ws (fast path) or fp32 w/ convert.
// grid=(4,64): the 4 n-tiles of an m-tile are dispatch-adjacent -> LLC dedups
// the A re-reads.
// ---------------------------------------------------------------------------
template <int ABF>
__global__ __launch_bounds__(256, 2) void k_gemm2(const float* __restrict__ A32,
                                                  const bhalf* __restrict__ A16,
                                                  const bhalf* __restrict__ ht,
                                                  const float* __restrict__ feat,
                                                  const float* __restrict__ rsr,
                                                  const int* __restrict__ flag,
                                                  float* __restrict__ out) {
    constexpr int LDA = 40;
    __shared__ __align__(16) bhalf lsA[128 * LDA];
    __shared__ __align__(16) bhalf lsB[128 * LDA];
    const int n0   = blockIdx.x * 128;
    const int m0   = blockIdx.y * 128;
    const int t    = threadIdx.x;
    const int lane = t & 63, wave = t >> 6;
    const int wm = (wave >> 1) * 64, wn = (wave & 1) * 64;
    const int qk = (lane >> 4) * 8, rsel = lane & 15;
    f32x4 acc[4][4];
#pragma unroll
    for (int a = 0; a < 4; ++a)
#pragma unroll
        for (int bq = 0; bq < 4; ++bq)
#pragma unroll
            for (int e = 0; e < 4; ++e) acc[a][bq][e] = 0.f;

    for (int k0 = 0; k0 < NN; k0 += 32) {
        if (ABF) {
#pragma unroll
            for (int i = 0; i < 2; ++i) {
                const int ch = i * 256 + t;  // 512 x 16B chunks
                const int r = ch >> 2, seg = ch & 3;
                const bhalf8 v =
                    *(const bhalf8*)(A16 + (size_t)(m0 + r) * NN + k0 + seg * 8);
                *(bhalf8*)(lsA + r * LDA + seg * 8) = v;
            }
        } else {
#pragma unroll
            for (int i = 0; i < 4; ++i) {
                const int ch = i * 256 + t;  // 1024 float4 chunks
                const int r = ch >> 3, seg = ch & 7;
                const float4 v =
                    *(const float4*)(A32 + (size_t)(m0 + r) * NN + k0 + seg * 4);
                bhalf4 o;
                o[0] = (bhalf)v.x; o[1] = (bhalf)v.y; o[2] = (bhalf)v.z; o[3] = (bhalf)v.w;
                *(bhalf4*)(lsA + r * LDA + seg * 4) = o;
            }
        }
#pragma unroll
        for (int i = 0; i < 2; ++i) {
            const int ch = i * 256 + t;
            const int r = ch >> 2, seg = ch & 3;
            const bhalf8 v = *(const bhalf8*)(ht + (size_t)(n0 + r) * NN + k0 + seg * 8);
            *(bhalf8*)(lsB + r * LDA + seg * 8) = v;
        }
        __syncthreads();
        bhalf8 af[4], bf[4];
#pragma unroll
        for (int x = 0; x < 4; ++x) {
            af[x] = *(const bhalf8*)(lsA + (wm + x * 16 + rsel) * LDA + qk);
            bf[x] = *(const bhalf8*)(lsB + (wn + x * 16 + rsel) * LDA + qk);
        }
#pragma unroll
        for (int mt = 0; mt < 4; ++mt)
#pragma unroll
            for (int nt = 0; nt < 4; ++nt)
                acc[mt][nt] = __builtin_amdgcn_mfma_f32_16x16x32_bf16(af[mt], bf[nt],
                                                                      acc[mt][nt], 0, 0, 0);
        __syncthreads();
    }
    const int fl = *flag;
#pragma unroll
    for (int mt = 0; mt < 4; ++mt) {
        const int ibase = m0 + wm + mt * 16 + (lane >> 4) * 4;
#pragma unroll
        for (int rg = 0; rg < 4; ++rg) {
            const int i   = ibase + rg;
            const float s = rsr[i];
#pragma unroll
            for (int nt = 0; nt < 4; ++nt) {
                const int j   = n0 + wn + nt * 16 + rsel;
                const float f = feat[(size_t)i * CC + j];
                out[(size_t)i * CC + j] = fl ? f : fmaf(s, acc[mt][nt][rg], f);
            }
        }
    }
}

// ---------------------------------------------------------------------------
// Workspace layout:
//   0        row_deg  f32[8192]
//   32768    col_deg  f32[8192]
//   65536    rsqrt_row f32[8192]
//   98304    rsqrt_col f32[8192]
//   131072   flag int
//   262144   ht bf16[512*8192]        (8 MB)
//   16777216 A_bf16 bf16[8192*8192]   (128 MB, only if ws_size allows)
// ---------------------------------------------------------------------------
extern "C" void kernel_launch(void* const* d_in, const int* in_sizes, int n_in,
                              void* d_out, int out_size, void* d_ws, size_t ws_size,
                              hipStream_t stream) {
    const float* feat = (const float*)d_in[0];
    const float* adj  = (const float*)d_in[1];
    const float* W    = (const float*)d_in[2];
    const float* bias = (const float*)d_in[3];
    float* out = (float*)d_out;

    char* ws       = (char*)d_ws;
    float* row_deg = (float*)(ws);
    float* col_deg = (float*)(ws + 32768);
    float* rsr     = (float*)(ws + 65536);
    float* rsc     = (float*)(ws + 98304);
    int* flag      = (int*)(ws + 131072);
    bhalf* ht      = (bhalf*)(ws + 262144);
    bhalf* Abf     = (bhalf*)(ws + 16777216);

    const bool use_bf16 =
        ws_size >= (size_t)16777216 + (size_t)NN * (size_t)NN * 2;

    hipMemsetAsync(d_ws, 0, 131072 + 64, stream);

    if (use_bf16)
        k_degrees<1><<<dim3(8, 128), 256, 0, stream>>>(adj, row_deg, col_deg, Abf);
    else
        k_degrees<0><<<dim3(8, 128), 256, 0, stream>>>(adj, row_deg, col_deg, nullptr);

    k_finalize<<<32, 256, 0, stream>>>(row_deg, col_deg, rsr, rsc, flag);

    k_h<<<dim3(4, 64), 256, 0, stream>>>(feat, W, bias, rsc, ht);

    if (use_bf16)
        k_gemm2<1><<<dim3(4, 64), 256, 0, stream>>>(adj, Abf, ht, feat, rsr, flag, out);
    else
        k_gemm2<0><<<dim3(4, 64), 256, 0, stream>>>(adj, nullptr, ht, feat, rsr, flag, out);
}

// Round 2
// 631.496 us; speedup vs baseline: 1.0107x; 1.0107x over previous
//
#include <hip/hip_runtime.h>

#define NN 8192
#define CC 512

typedef __bf16 bhalf;
typedef bhalf bhalf8 __attribute__((ext_vector_type(8)));
typedef bhalf bhalf4 __attribute__((ext_vector_type(4)));
typedef float f32x4 __attribute__((ext_vector_type(4)));

// Swizzled LDS offset (in shorts) for the 16B chunk `seg` (0..3) of `row` in a
// [128][32]-short tile. Layout: [pair of rows = 64 shorts][8 slots x 8 shorts],
// slot = ((row&1)*4 + seg) ^ (pair & 7).
// For a wave64 ds_read_b128 (quad q reads chunk q of rows base..base+15) this
// covers all 8 bank-quad positions exactly 2x per 16 lanes -> 2-way = free
// (m136), and every offset is 16B-aligned (b128-legal).
__device__ __forceinline__ int sw_off(int row, int seg) {
    const int p = row >> 1;
    const int slot = (((row & 1) << 2) | seg) ^ (p & 7);
    return p * 64 + slot * 8;
}

// ---------------------------------------------------------------------------
// Pass 1: degree sums over A (one full read), optionally emitting A as bf16.
// Tile: 32 rows x 1024 cols. grid = (8, 256) = 2048 blocks, LDS 32 KB
// (4-5 blocks/CU vs round-1's 2).
// ---------------------------------------------------------------------------
template <int WRITE_BF16>
__global__ __launch_bounds__(256) void k_degrees(const float* __restrict__ A,
                                                 float* __restrict__ row_deg,
                                                 float* __restrict__ col_deg,
                                                 bhalf* __restrict__ Abf) {
    __shared__ float rp[32 * 256];  // 32 KB
    const int t  = threadIdx.x;
    const int c  = blockIdx.x * 1024 + t * 4;
    const int r0 = blockIdx.y * 32;
    float c0 = 0.f, c1 = 0.f, c2 = 0.f, c3 = 0.f;
#pragma unroll 8
    for (int r = 0; r < 32; ++r) {
        const float4 v = *(const float4*)(A + (size_t)(r0 + r) * NN + c);
        c0 += v.x; c1 += v.y; c2 += v.z; c3 += v.w;
        rp[r * 256 + t] = (v.x + v.y) + (v.z + v.w);
        if (WRITE_BF16) {
            bhalf4 o;
            o[0] = (bhalf)v.x; o[1] = (bhalf)v.y; o[2] = (bhalf)v.z; o[3] = (bhalf)v.w;
            *(bhalf4*)(Abf + (size_t)(r0 + r) * NN + c) = o;
        }
    }
    atomicAdd(&col_deg[c + 0], c0);
    atomicAdd(&col_deg[c + 1], c1);
    atomicAdd(&col_deg[c + 2], c2);
    atomicAdd(&col_deg[c + 3], c3);
    __syncthreads();
    // 8 threads per row; staggered reads -> 2-way bank alias max (free)
    const int r = t >> 3;
    const int g = (t & 7) * 32;
    float s = 0.f;
#pragma unroll 8
    for (int i = 0; i < 32; ++i) s += rp[r * 256 + g + ((i + t) & 31)];
    atomicAdd(&row_deg[r0 + r], s);
}

// ---------------------------------------------------------------------------
// Pass 2: rsqrt of degrees + zero flag. 8192 elems.
// ---------------------------------------------------------------------------
__global__ __launch_bounds__(256) void k_finalize(const float* __restrict__ rd,
                                                  const float* __restrict__ cd,
                                                  float* __restrict__ rsr,
                                                  float* __restrict__ rsc,
                                                  int* __restrict__ flag) {
    const int i = blockIdx.x * 256 + threadIdx.x;
    const float r = rd[i], c = cd[i];
    rsr[i] = (r > 0.f) ? rsqrtf(r) : 0.f;
    rsc[i] = (c > 0.f) ? rsqrtf(c) : 0.f;
    if (r == 0.f || c == 0.f) atomicExch(flag, 1);
}

// ---------------------------------------------------------------------------
// Pass 3: ht[n][k] = relu( sum_c feat[k][c]*W[n][c] + b[n] ) * rsqrt_col[k]
// stored bf16, K-contiguous. 128x128 tile, BK=32, 16x16x32 MFMA. grid=(4,64).
// ---------------------------------------------------------------------------
__global__ __launch_bounds__(256, 2) void k_h(const float* __restrict__ feat,
                                              const float* __restrict__ W,
                                              const float* __restrict__ bias,
                                              const float* __restrict__ rsc,
                                              bhalf* __restrict__ ht) {
    __shared__ __align__(16) bhalf lsA[128 * 32];
    __shared__ __align__(16) bhalf lsB[128 * 32];
    const int n0   = blockIdx.x * 128;  // output-feature tile
    const int m0   = blockIdx.y * 128;  // k-row tile
    const int t    = threadIdx.x;
    const int lane = t & 63, wave = t >> 6;
    const int wm = (wave >> 1) * 64, wn = (wave & 1) * 64;
    const int quad = lane >> 4, rsel = lane & 15;
    f32x4 acc[4][4];
#pragma unroll
    for (int a = 0; a < 4; ++a)
#pragma unroll
        for (int bq = 0; bq < 4; ++bq)
#pragma unroll
            for (int e = 0; e < 4; ++e) acc[a][bq][e] = 0.f;

    for (int k0 = 0; k0 < CC; k0 += 32) {
#pragma unroll
        for (int i = 0; i < 4; ++i) {
            const int ch = i * 256 + t;  // 1024 float4 chunks per operand
            const int r = ch >> 3, s8 = ch & 7;
            const int lo = sw_off(r, s8 >> 1) + (s8 & 1) * 4;
            const float4 v = *(const float4*)(feat + (size_t)(m0 + r) * CC + k0 + s8 * 4);
            bhalf4 o;
            o[0] = (bhalf)v.x; o[1] = (bhalf)v.y; o[2] = (bhalf)v.z; o[3] = (bhalf)v.w;
            *(bhalf4*)(lsA + lo) = o;
            const float4 w = *(const float4*)(W + (size_t)(n0 + r) * CC + k0 + s8 * 4);
            bhalf4 ow;
            ow[0] = (bhalf)w.x; ow[1] = (bhalf)w.y; ow[2] = (bhalf)w.z; ow[3] = (bhalf)w.w;
            *(bhalf4*)(lsB + lo) = ow;
        }
        __syncthreads();
        bhalf8 af[4], bf[4];
#pragma unroll
        for (int x = 0; x < 4; ++x) {
            af[x] = *(const bhalf8*)(lsA + sw_off(wm + x * 16 + rsel, quad));
            bf[x] = *(const bhalf8*)(lsB + sw_off(wn + x * 16 + rsel, quad));
        }
#pragma unroll
        for (int mt = 0; mt < 4; ++mt)
#pragma unroll
            for (int nt = 0; nt < 4; ++nt)
                acc[mt][nt] = __builtin_amdgcn_mfma_f32_16x16x32_bf16(af[mt], bf[nt],
                                                                      acc[mt][nt], 0, 0, 0);
        __syncthreads();
    }
#pragma unroll
    for (int mt = 0; mt < 4; ++mt) {
        const int kbase = m0 + wm + mt * 16 + quad * 4;
        const float s0 = rsc[kbase + 0], s1 = rsc[kbase + 1];
        const float s2 = rsc[kbase + 2], s3 = rsc[kbase + 3];
#pragma unroll
        for (int nt = 0; nt < 4; ++nt) {
            const int n = n0 + wn + nt * 16 + rsel;
            const float bn = bias[n];
            bhalf4 o;
            o[0] = (bhalf)(fmaxf(acc[mt][nt][0] + bn, 0.f) * s0);
            o[1] = (bhalf)(fmaxf(acc[mt][nt][1] + bn, 0.f) * s1);
            o[2] = (bhalf)(fmaxf(acc[mt][nt][2] + bn, 0.f) * s2);
            o[3] = (bhalf)(fmaxf(acc[mt][nt][3] + bn, 0.f) * s3);
            *(bhalf4*)(ht + (size_t)n * NN + kbase) = o;
        }
    }
}

// ---------------------------------------------------------------------------
// Pass 4: out += rsr[i] * (A_tile @ ht_tile) via K-split-4 + atomics.
// out is pre-initialized to feat (d2d copy); if flag, no adds happen.
// grid = (4, 64, 4) = 1024 blocks -> ~3-4 blocks/CU so staging of one block
// overlaps MFMA of another (m114 wave-level overlap).
// ---------------------------------------------------------------------------
template <int ABF>
__global__ __launch_bounds__(256, 3) void k_gemm2(const float* __restrict__ A32,
                                                  const bhalf* __restrict__ A16,
                                                  const bhalf* __restrict__ ht,
                                                  const float* __restrict__ rsr,
                                                  const int* __restrict__ flag,
                                                  float* __restrict__ out) {
    __shared__ __align__(16) bhalf lsA[128 * 32];
    __shared__ __align__(16) bhalf lsB[128 * 32];
    const int n0   = blockIdx.x * 128;
    const int m0   = blockIdx.y * 128;
    const int K0   = blockIdx.z * (NN / 4);
    const int t    = threadIdx.x;
    const int lane = t & 63, wave = t >> 6;
    const int wm = (wave >> 1) * 64, wn = (wave & 1) * 64;
    const int quad = lane >> 4, rsel = lane & 15;
    f32x4 acc[4][4];
#pragma unroll
    for (int a = 0; a < 4; ++a)
#pragma unroll
        for (int bq = 0; bq < 4; ++bq)
#pragma unroll
            for (int e = 0; e < 4; ++e) acc[a][bq][e] = 0.f;

    for (int k0 = K0; k0 < K0 + NN / 4; k0 += 32) {
        if (ABF) {
#pragma unroll
            for (int i = 0; i < 2; ++i) {
                const int ch = i * 256 + t;  // 512 x 16B chunks
                const int r = ch >> 2, seg = ch & 3;
                const bhalf8 v =
                    *(const bhalf8*)(A16 + (size_t)(m0 + r) * NN + k0 + seg * 8);
                *(bhalf8*)(lsA + sw_off(r, seg)) = v;
            }
        } else {
#pragma unroll
            for (int i = 0; i < 4; ++i) {
                const int ch = i * 256 + t;  // 1024 float4 chunks
                const int r = ch >> 3, s8 = ch & 7;
                const float4 v =
                    *(const float4*)(A32 + (size_t)(m0 + r) * NN + k0 + s8 * 4);
                bhalf4 o;
                o[0] = (bhalf)v.x; o[1] = (bhalf)v.y; o[2] = (bhalf)v.z; o[3] = (bhalf)v.w;
                *(bhalf4*)(lsA + sw_off(r, s8 >> 1) + (s8 & 1) * 4) = o;
            }
        }
#pragma unroll
        for (int i = 0; i < 2; ++i) {
            const int ch = i * 256 + t;
            const int r = ch >> 2, seg = ch & 3;
            const bhalf8 v = *(const bhalf8*)(ht + (size_t)(n0 + r) * NN + k0 + seg * 8);
            *(bhalf8*)(lsB + sw_off(r, seg)) = v;
        }
        __syncthreads();
        bhalf8 af[4], bf[4];
#pragma unroll
        for (int x = 0; x < 4; ++x) {
            af[x] = *(const bhalf8*)(lsA + sw_off(wm + x * 16 + rsel, quad));
            bf[x] = *(const bhalf8*)(lsB + sw_off(wn + x * 16 + rsel, quad));
        }
#pragma unroll
        for (int mt = 0; mt < 4; ++mt)
#pragma unroll
            for (int nt = 0; nt < 4; ++nt)
                acc[mt][nt] = __builtin_amdgcn_mfma_f32_16x16x32_bf16(af[mt], bf[nt],
                                                                      acc[mt][nt], 0, 0, 0);
        __syncthreads();
    }
    const int fl = *flag;
    if (fl) return;  // out already = feat
#pragma unroll
    for (int mt = 0; mt < 4; ++mt) {
        const int ibase = m0 + wm + mt * 16 + quad * 4;
#pragma unroll
        for (int rg = 0; rg < 4; ++rg) {
            const int i   = ibase + rg;
            const float s = rsr[i];
#pragma unroll
            for (int nt = 0; nt < 4; ++nt) {
                const int j = n0 + wn + nt * 16 + rsel;
                atomicAdd(&out[(size_t)i * CC + j], s * acc[mt][nt][rg]);
            }
        }
    }
}

// ---------------------------------------------------------------------------
// Workspace layout:
//   0        row_deg  f32[8192]
//   32768    col_deg  f32[8192]
//   65536    rsqrt_row f32[8192]
//   98304    rsqrt_col f32[8192]
//   131072   flag int
//   262144   ht bf16[512*8192]        (8 MB)
//   16777216 A_bf16 bf16[8192*8192]   (128 MB, only if ws_size allows)
// ---------------------------------------------------------------------------
extern "C" void kernel_launch(void* const* d_in, const int* in_sizes, int n_in,
                              void* d_out, int out_size, void* d_ws, size_t ws_size,
                              hipStream_t stream) {
    const float* feat = (const float*)d_in[0];
    const float* adj  = (const float*)d_in[1];
    const float* W    = (const float*)d_in[2];
    const float* bias = (const float*)d_in[3];
    float* out = (float*)d_out;

    char* ws       = (char*)d_ws;
    float* row_deg = (float*)(ws);
    float* col_deg = (float*)(ws + 32768);
    float* rsr     = (float*)(ws + 65536);
    float* rsc     = (float*)(ws + 98304);
    int* flag      = (int*)(ws + 131072);
    bhalf* ht      = (bhalf*)(ws + 262144);
    bhalf* Abf     = (bhalf*)(ws + 16777216);

    const bool use_bf16 =
        ws_size >= (size_t)16777216 + (size_t)NN * (size_t)NN * 2;

    hipMemsetAsync(d_ws, 0, 131072 + 64, stream);
    // out = identity (feat); gemm2 atomically accumulates on top
    hipMemcpyAsync(out, feat, (size_t)NN * CC * sizeof(float),
                   hipMemcpyDeviceToDevice, stream);

    if (use_bf16)
        k_degrees<1><<<dim3(8, 256), 256, 0, stream>>>(adj, row_deg, col_deg, Abf);
    else
        k_degrees<0><<<dim3(8, 256), 256, 0, stream>>>(adj, row_deg, col_deg, nullptr);

    k_finalize<<<32, 256, 0, stream>>>(row_deg, col_deg, rsr, rsc, flag);

    k_h<<<dim3(4, 64), 256, 0, stream>>>(feat, W, bias, rsc, ht);

    if (use_bf16)
        k_gemm2<1><<<dim3(4, 64, 4), 256, 0, stream>>>(adj, Abf, ht, rsr, flag, out);
    else
        k_gemm2<0><<<dim3(4, 64, 4), 256, 0, stream>>>(adj, nullptr, ht, rsr, flag, out);
}

// Round 3
// 591.355 us; speedup vs baseline: 1.0793x; 1.0679x over previous
//
#include <hip/hip_runtime.h>

#define NN 8192
#define CC 512

typedef __bf16 bhalf;
typedef bhalf bhalf8 __attribute__((ext_vector_type(8)));
typedef bhalf bhalf4 __attribute__((ext_vector_type(4)));
typedef float f32x4 __attribute__((ext_vector_type(4)));

// Swizzled LDS offset (in shorts) for the 16B chunk `seg` (0..3) of `row` in a
// [128][32]-short tile. slot = ((row&1)*4 + seg) ^ (pair & 7); all 8
// b128-aligned bank positions covered, exactly 2-way aliasing (free, m136).
__device__ __forceinline__ int sw_off(int row, int seg) {
    const int p = row >> 1;
    const int slot = (((row & 1) << 2) | seg) ^ (p & 7);
    return p * 64 + slot * 8;
}

// ---------------------------------------------------------------------------
// out = feat, as a kernel (NOT hipMemcpyAsync: D2D memcpy in a graph runs on
// the SDMA engine at ~0.1 TB/s -> ~200us hidden; this kernel is ~6us).
// ---------------------------------------------------------------------------
__global__ __launch_bounds__(256) void k_copy(const float4* __restrict__ src,
                                              float4* __restrict__ dst) {
    const int i = blockIdx.x * 256 + threadIdx.x;
    dst[i] = src[i];
}

// ---------------------------------------------------------------------------
// Pass 1: degree sums over A (one full read) + A -> bf16 emit.
// Block = 4 waves; wave owns 8 rows x 256 cols (one float4-coalesced load per
// row per lane). Row sums: 6-step shuffle tree (VALU was 4% idle). Col sums:
// 4 per-lane regs -> 1KB LDS combine -> one atomic per col per block.
// grid (32, 256) = 8192 blocks, tiny LDS -> full occupancy, ~8 outstanding
// loads/lane. Predict ~75us vs round-2's 186.
// ---------------------------------------------------------------------------
template <int WRITE_BF16>
__global__ __launch_bounds__(256) void k_degrees(const float* __restrict__ A,
                                                 float* __restrict__ row_deg,
                                                 float* __restrict__ col_deg,
                                                 bhalf* __restrict__ Abf) {
    __shared__ float lcol[256];
    const int t    = threadIdx.x;
    const int lane = t & 63, wave = t >> 6;
    const int c0 = blockIdx.x * 256;
    const int r0 = blockIdx.y * 32 + wave * 8;
    const int c  = c0 + lane * 4;
    lcol[t] = 0.f;
    __syncthreads();

    float p0 = 0.f, p1 = 0.f, p2 = 0.f, p3 = 0.f;
    float rs[8];
#pragma unroll
    for (int r = 0; r < 8; ++r) {
        const float4 v = *(const float4*)(A + (size_t)(r0 + r) * NN + c);
        if (WRITE_BF16) {
            bhalf4 o;
            o[0] = (bhalf)v.x; o[1] = (bhalf)v.y; o[2] = (bhalf)v.z; o[3] = (bhalf)v.w;
            *(bhalf4*)(Abf + (size_t)(r0 + r) * NN + c) = o;
        }
        p0 += v.x; p1 += v.y; p2 += v.z; p3 += v.w;
        rs[r] = (v.x + v.y) + (v.z + v.w);
    }
    // 8 independent shuffle-reduce trees (compiler interleaves them)
#pragma unroll
    for (int r = 0; r < 8; ++r) {
#pragma unroll
        for (int off = 32; off; off >>= 1) rs[r] += __shfl_xor(rs[r], off, 64);
    }
    if (lane == 0) {
#pragma unroll
        for (int r = 0; r < 8; ++r) atomicAdd(&row_deg[r0 + r], rs[r]);
    }
    atomicAdd(&lcol[lane * 4 + 0], p0);
    atomicAdd(&lcol[lane * 4 + 1], p1);
    atomicAdd(&lcol[lane * 4 + 2], p2);
    atomicAdd(&lcol[lane * 4 + 3], p3);
    __syncthreads();
    atomicAdd(&col_deg[c0 + t], lcol[t]);
}

// ---------------------------------------------------------------------------
// Pass 2: rsqrt of degrees + zero flag. 8192 elems.
// ---------------------------------------------------------------------------
__global__ __launch_bounds__(256) void k_finalize(const float* __restrict__ rd,
                                                  const float* __restrict__ cd,
                                                  float* __restrict__ rsr,
                                                  float* __restrict__ rsc,
                                                  int* __restrict__ flag) {
    const int i = blockIdx.x * 256 + threadIdx.x;
    const float r = rd[i], c = cd[i];
    rsr[i] = (r > 0.f) ? rsqrtf(r) : 0.f;
    rsc[i] = (c > 0.f) ? rsqrtf(c) : 0.f;
    if (r == 0.f || c == 0.f) atomicExch(flag, 1);
}

// ---------------------------------------------------------------------------
// Pass 3: ht[n][k] = relu( sum_c feat[k][c]*W[n][c] + b[n] ) * rsqrt_col[k]
// stored bf16, K-contiguous. 128x128 tile, BK=32, 16x16x32 MFMA. grid=(4,64).
// ---------------------------------------------------------------------------
__global__ __launch_bounds__(256, 2) void k_h(const float* __restrict__ feat,
                                              const float* __restrict__ W,
                                              const float* __restrict__ bias,
                                              const float* __restrict__ rsc,
                                              bhalf* __restrict__ ht) {
    __shared__ __align__(16) bhalf lsA[128 * 32];
    __shared__ __align__(16) bhalf lsB[128 * 32];
    const int n0   = blockIdx.x * 128;  // output-feature tile
    const int m0   = blockIdx.y * 128;  // k-row tile
    const int t    = threadIdx.x;
    const int lane = t & 63, wave = t >> 6;
    const int wm = (wave >> 1) * 64, wn = (wave & 1) * 64;
    const int quad = lane >> 4, rsel = lane & 15;
    f32x4 acc[4][4];
#pragma unroll
    for (int a = 0; a < 4; ++a)
#pragma unroll
        for (int bq = 0; bq < 4; ++bq)
#pragma unroll
            for (int e = 0; e < 4; ++e) acc[a][bq][e] = 0.f;

    for (int k0 = 0; k0 < CC; k0 += 32) {
#pragma unroll
        for (int i = 0; i < 4; ++i) {
            const int ch = i * 256 + t;  // 1024 float4 chunks per operand
            const int r = ch >> 3, s8 = ch & 7;
            const int lo = sw_off(r, s8 >> 1) + (s8 & 1) * 4;
            const float4 v = *(const float4*)(feat + (size_t)(m0 + r) * CC + k0 + s8 * 4);
            bhalf4 o;
            o[0] = (bhalf)v.x; o[1] = (bhalf)v.y; o[2] = (bhalf)v.z; o[3] = (bhalf)v.w;
            *(bhalf4*)(lsA + lo) = o;
            const float4 w = *(const float4*)(W + (size_t)(n0 + r) * CC + k0 + s8 * 4);
            bhalf4 ow;
            ow[0] = (bhalf)w.x; ow[1] = (bhalf)w.y; ow[2] = (bhalf)w.z; ow[3] = (bhalf)w.w;
            *(bhalf4*)(lsB + lo) = ow;
        }
        __syncthreads();
        bhalf8 af[4], bf[4];
#pragma unroll
        for (int x = 0; x < 4; ++x) {
            af[x] = *(const bhalf8*)(lsA + sw_off(wm + x * 16 + rsel, quad));
            bf[x] = *(const bhalf8*)(lsB + sw_off(wn + x * 16 + rsel, quad));
        }
#pragma unroll
        for (int mt = 0; mt < 4; ++mt)
#pragma unroll
            for (int nt = 0; nt < 4; ++nt)
                acc[mt][nt] = __builtin_amdgcn_mfma_f32_16x16x32_bf16(af[mt], bf[nt],
                                                                      acc[mt][nt], 0, 0, 0);
        __syncthreads();
    }
#pragma unroll
    for (int mt = 0; mt < 4; ++mt) {
        const int kbase = m0 + wm + mt * 16 + quad * 4;
        const float s0 = rsc[kbase + 0], s1 = rsc[kbase + 1];
        const float s2 = rsc[kbase + 2], s3 = rsc[kbase + 3];
#pragma unroll
        for (int nt = 0; nt < 4; ++nt) {
            const int n = n0 + wn + nt * 16 + rsel;
            const float bn = bias[n];
            bhalf4 o;
            o[0] = (bhalf)(fmaxf(acc[mt][nt][0] + bn, 0.f) * s0);
            o[1] = (bhalf)(fmaxf(acc[mt][nt][1] + bn, 0.f) * s1);
            o[2] = (bhalf)(fmaxf(acc[mt][nt][2] + bn, 0.f) * s2);
            o[3] = (bhalf)(fmaxf(acc[mt][nt][3] + bn, 0.f) * s3);
            *(bhalf4*)(ht + (size_t)n * NN + kbase) = o;
        }
    }
}

// ---------------------------------------------------------------------------
// Pass 4: out += rsr[i] * (A_tile @ ht_tile) via K-split-4 + atomics.
// out pre-initialized to feat by k_copy; if flag, no adds happen.
// grid (4,64,4) = 1024 blocks (~3-4/CU for wave-level overlap, m114).
// ---------------------------------------------------------------------------
template <int ABF>
__global__ __launch_bounds__(256, 3) void k_gemm2(const float* __restrict__ A32,
                                                  const bhalf* __restrict__ A16,
                                                  const bhalf* __restrict__ ht,
                                                  const float* __restrict__ rsr,
                                                  const int* __restrict__ flag,
                                                  float* __restrict__ out) {
    __shared__ __align__(16) bhalf lsA[128 * 32];
    __shared__ __align__(16) bhalf lsB[128 * 32];
    const int n0   = blockIdx.x * 128;
    const int m0   = blockIdx.y * 128;
    const int K0   = blockIdx.z * (NN / 4);
    const int t    = threadIdx.x;
    const int lane = t & 63, wave = t >> 6;
    const int wm = (wave >> 1) * 64, wn = (wave & 1) * 64;
    const int quad = lane >> 4, rsel = lane & 15;
    f32x4 acc[4][4];
#pragma unroll
    for (int a = 0; a < 4; ++a)
#pragma unroll
        for (int bq = 0; bq < 4; ++bq)
#pragma unroll
            for (int e = 0; e < 4; ++e) acc[a][bq][e] = 0.f;

    for (int k0 = K0; k0 < K0 + NN / 4; k0 += 32) {
        if (ABF) {
#pragma unroll
            for (int i = 0; i < 2; ++i) {
                const int ch = i * 256 + t;  // 512 x 16B chunks
                const int r = ch >> 2, seg = ch & 3;
                const bhalf8 v =
                    *(const bhalf8*)(A16 + (size_t)(m0 + r) * NN + k0 + seg * 8);
                *(bhalf8*)(lsA + sw_off(r, seg)) = v;
            }
        } else {
#pragma unroll
            for (int i = 0; i < 4; ++i) {
                const int ch = i * 256 + t;  // 1024 float4 chunks
                const int r = ch >> 3, s8 = ch & 7;
                const float4 v =
                    *(const float4*)(A32 + (size_t)(m0 + r) * NN + k0 + s8 * 4);
                bhalf4 o;
                o[0] = (bhalf)v.x; o[1] = (bhalf)v.y; o[2] = (bhalf)v.z; o[3] = (bhalf)v.w;
                *(bhalf4*)(lsA + sw_off(r, s8 >> 1) + (s8 & 1) * 4) = o;
            }
        }
#pragma unroll
        for (int i = 0; i < 2; ++i) {
            const int ch = i * 256 + t;
            const int r = ch >> 2, seg = ch & 3;
            const bhalf8 v = *(const bhalf8*)(ht + (size_t)(n0 + r) * NN + k0 + seg * 8);
            *(bhalf8*)(lsB + sw_off(r, seg)) = v;
        }
        __syncthreads();
        bhalf8 af[4], bf[4];
#pragma unroll
        for (int x = 0; x < 4; ++x) {
            af[x] = *(const bhalf8*)(lsA + sw_off(wm + x * 16 + rsel, quad));
            bf[x] = *(const bhalf8*)(lsB + sw_off(wn + x * 16 + rsel, quad));
        }
#pragma unroll
        for (int mt = 0; mt < 4; ++mt)
#pragma unroll
            for (int nt = 0; nt < 4; ++nt)
                acc[mt][nt] = __builtin_amdgcn_mfma_f32_16x16x32_bf16(af[mt], bf[nt],
                                                                      acc[mt][nt], 0, 0, 0);
        __syncthreads();
    }
    const int fl = *flag;
    if (fl) return;  // out already = feat
#pragma unroll
    for (int mt = 0; mt < 4; ++mt) {
        const int ibase = m0 + wm + mt * 16 + quad * 4;
#pragma unroll
        for (int rg = 0; rg < 4; ++rg) {
            const int i   = ibase + rg;
            const float s = rsr[i];
#pragma unroll
            for (int nt = 0; nt < 4; ++nt) {
                const int j = n0 + wn + nt * 16 + rsel;
                atomicAdd(&out[(size_t)i * CC + j], s * acc[mt][nt][rg]);
            }
        }
    }
}

// ---------------------------------------------------------------------------
// Workspace layout:
//   0        row_deg  f32[8192]
//   32768    col_deg  f32[8192]
//   65536    rsqrt_row f32[8192]
//   98304    rsqrt_col f32[8192]
//   131072   flag int
//   262144   ht bf16[512*8192]        (8 MB)
//   16777216 A_bf16 bf16[8192*8192]   (128 MB, only if ws_size allows)
// ---------------------------------------------------------------------------
extern "C" void kernel_launch(void* const* d_in, const int* in_sizes, int n_in,
                              void* d_out, int out_size, void* d_ws, size_t ws_size,
                              hipStream_t stream) {
    const float* feat = (const float*)d_in[0];
    const float* adj  = (const float*)d_in[1];
    const float* W    = (const float*)d_in[2];
    const float* bias = (const float*)d_in[3];
    float* out = (float*)d_out;

    char* ws       = (char*)d_ws;
    float* row_deg = (float*)(ws);
    float* col_deg = (float*)(ws + 32768);
    float* rsr     = (float*)(ws + 65536);
    float* rsc     = (float*)(ws + 98304);
    int* flag      = (int*)(ws + 131072);
    bhalf* ht      = (bhalf*)(ws + 262144);
    bhalf* Abf     = (bhalf*)(ws + 16777216);

    const bool use_bf16 =
        ws_size >= (size_t)16777216 + (size_t)NN * (size_t)NN * 2;

    hipMemsetAsync(d_ws, 0, 131072 + 64, stream);
    // out = identity (feat); gemm2 atomically accumulates on top
    k_copy<<<NN * CC / 4 / 256, 256, 0, stream>>>((const float4*)feat, (float4*)out);

    if (use_bf16)
        k_degrees<1><<<dim3(32, 256), 256, 0, stream>>>(adj, row_deg, col_deg, Abf);
    else
        k_degrees<0><<<dim3(32, 256), 256, 0, stream>>>(adj, row_deg, col_deg, nullptr);

    k_finalize<<<32, 256, 0, stream>>>(row_deg, col_deg, rsr, rsc, flag);

    k_h<<<dim3(4, 64), 256, 0, stream>>>(feat, W, bias, rsc, ht);

    if (use_bf16)
        k_gemm2<1><<<dim3(4, 64, 4), 256, 0, stream>>>(adj, Abf, ht, rsr, flag, out);
    else
        k_gemm2<0><<<dim3(4, 64, 4), 256, 0, stream>>>(adj, nullptr, ht, rsr, flag, out);
}

// Round 4
// 534.058 us; speedup vs baseline: 1.1951x; 1.1073x over previous
//
#include <hip/hip_runtime.h>

#define NN 8192
#define CC 512

typedef __bf16 bhalf;
typedef bhalf bhalf8 __attribute__((ext_vector_type(8)));
typedef bhalf bhalf4 __attribute__((ext_vector_type(4)));
typedef float f32x4 __attribute__((ext_vector_type(4)));

#define AS1 __attribute__((address_space(1)))
#define AS3 __attribute__((address_space(3)))
// async 16B/lane global->LDS; LDS dest = wave-uniform base + lane*16
#define GLL16(g, l) \
    __builtin_amdgcn_global_load_lds((const AS1 void*)(g), (AS3 void*)(l), 16, 0, 0)

// Swizzled LDS offset (in shorts) for the 16B chunk `seg` (0..3) of `row` in a
// [rows][32]-short tile. slot = ((row&1)*4 + seg) ^ (pair & 7); all 8
// b128-aligned bank positions covered, exactly 2-way aliasing (free, m136).
// Compatible with GLL16: a 1KB chunk (16 rows, base row % 16 == 0) staged with
// lane -> (row = 2*(lane>>3) + (x>>2), seg = x&3), x = (lane&7)^(lane>>3)
// lands at chunkbase + lane*16 == sw_off of that (row,seg).  (verified algebra)
__device__ __forceinline__ int sw_off(int row, int seg) {
    const int p = row >> 1;
    const int slot = (((row & 1) << 2) | seg) ^ (p & 7);
    return p * 64 + slot * 8;
}

// ---------------------------------------------------------------------------
// out = feat, as a kernel (graph-D2D memcpy uses slow SDMA).
// ---------------------------------------------------------------------------
__global__ __launch_bounds__(256) void k_copy(const float4* __restrict__ src,
                                              float4* __restrict__ dst) {
    const int i = blockIdx.x * 256 + threadIdx.x;
    dst[i] = src[i];
}

// ---------------------------------------------------------------------------
// Pass 1: degree sums over A (one full read) + A -> bf16 emit.
// Wave owns 8 rows x 1024 cols (4 float4 col-chunks/row): the 48-shuffle
// row-reduce tree is amortized over 512 B/lane (4x round-3). grid (8,256).
// ---------------------------------------------------------------------------
template <int WRITE_BF16>
__global__ __launch_bounds__(256) void k_degrees(const float* __restrict__ A,
                                                 float* __restrict__ row_deg,
                                                 float* __restrict__ col_deg,
                                                 bhalf* __restrict__ Abf) {
    __shared__ float lcol[1024];
    const int t    = threadIdx.x;
    const int lane = t & 63, wave = t >> 6;
    const int c0 = blockIdx.x * 1024;
    const int r0 = blockIdx.y * 32 + wave * 8;
    lcol[t] = 0.f; lcol[t + 256] = 0.f; lcol[t + 512] = 0.f; lcol[t + 768] = 0.f;
    __syncthreads();

    float colp[16];
#pragma unroll
    for (int j = 0; j < 16; ++j) colp[j] = 0.f;
    float rs[8];
#pragma unroll
    for (int r = 0; r < 8; ++r) rs[r] = 0.f;

#pragma unroll
    for (int ch = 0; ch < 4; ++ch) {
        const int c = c0 + ch * 256 + lane * 4;
#pragma unroll
        for (int r = 0; r < 8; ++r) {
            const float4 v = *(const float4*)(A + (size_t)(r0 + r) * NN + c);
            if (WRITE_BF16) {
                bhalf4 o;
                o[0] = (bhalf)v.x; o[1] = (bhalf)v.y; o[2] = (bhalf)v.z; o[3] = (bhalf)v.w;
                *(bhalf4*)(Abf + (size_t)(r0 + r) * NN + c) = o;
            }
            colp[ch * 4 + 0] += v.x; colp[ch * 4 + 1] += v.y;
            colp[ch * 4 + 2] += v.z; colp[ch * 4 + 3] += v.w;
            rs[r] += (v.x + v.y) + (v.z + v.w);
        }
    }
#pragma unroll
    for (int r = 0; r < 8; ++r) {
#pragma unroll
        for (int off = 32; off; off >>= 1) rs[r] += __shfl_xor(rs[r], off, 64);
    }
    if (lane == 0) {
#pragma unroll
        for (int r = 0; r < 8; ++r) atomicAdd(&row_deg[r0 + r], rs[r]);
    }
#pragma unroll
    for (int ch = 0; ch < 4; ++ch)
#pragma unroll
        for (int j = 0; j < 4; ++j)
            atomicAdd(&lcol[ch * 256 + lane * 4 + j], colp[ch * 4 + j]);
    __syncthreads();
#pragma unroll
    for (int ch = 0; ch < 4; ++ch)
        atomicAdd(&col_deg[c0 + ch * 256 + t], lcol[ch * 256 + t]);
}

// ---------------------------------------------------------------------------
// Pass 2: rsqrt of degrees + zero flag.
// ---------------------------------------------------------------------------
__global__ __launch_bounds__(256) void k_finalize(const float* __restrict__ rd,
                                                  const float* __restrict__ cd,
                                                  float* __restrict__ rsr,
                                                  float* __restrict__ rsc,
                                                  int* __restrict__ flag) {
    const int i = blockIdx.x * 256 + threadIdx.x;
    const float r = rd[i], c = cd[i];
    rsr[i] = (r > 0.f) ? rsqrtf(r) : 0.f;
    rsc[i] = (c > 0.f) ? rsqrtf(c) : 0.f;
    if (r == 0.f || c == 0.f) atomicExch(flag, 1);
}

// ---------------------------------------------------------------------------
// Pass 3: ht[n][k] = relu( sum_c feat[k][c]*W[n][c] + b[n] ) * rsqrt_col[k]
// stored bf16, K-contiguous. 128x128 tile, BK=32, 16x16x32 MFMA. grid=(4,64).
// ---------------------------------------------------------------------------
__global__ __launch_bounds__(256, 2) void k_h(const float* __restrict__ feat,
                                              const float* __restrict__ W,
                                              const float* __restrict__ bias,
                                              const float* __restrict__ rsc,
                                              bhalf* __restrict__ ht) {
    __shared__ __align__(16) bhalf lsA[128 * 32];
    __shared__ __align__(16) bhalf lsB[128 * 32];
    const int n0   = blockIdx.x * 128;
    const int m0   = blockIdx.y * 128;
    const int t    = threadIdx.x;
    const int lane = t & 63, wave = t >> 6;
    const int wm = (wave >> 1) * 64, wn = (wave & 1) * 64;
    const int quad = lane >> 4, rsel = lane & 15;
    f32x4 acc[4][4];
#pragma unroll
    for (int a = 0; a < 4; ++a)
#pragma unroll
        for (int bq = 0; bq < 4; ++bq)
#pragma unroll
            for (int e = 0; e < 4; ++e) acc[a][bq][e] = 0.f;

    for (int k0 = 0; k0 < CC; k0 += 32) {
#pragma unroll
        for (int i = 0; i < 4; ++i) {
            const int ch = i * 256 + t;
            const int r = ch >> 3, s8 = ch & 7;
            const int lo = sw_off(r, s8 >> 1) + (s8 & 1) * 4;
            const float4 v = *(const float4*)(feat + (size_t)(m0 + r) * CC + k0 + s8 * 4);
            bhalf4 o;
            o[0] = (bhalf)v.x; o[1] = (bhalf)v.y; o[2] = (bhalf)v.z; o[3] = (bhalf)v.w;
            *(bhalf4*)(lsA + lo) = o;
            const float4 w = *(const float4*)(W + (size_t)(n0 + r) * CC + k0 + s8 * 4);
            bhalf4 ow;
            ow[0] = (bhalf)w.x; ow[1] = (bhalf)w.y; ow[2] = (bhalf)w.z; ow[3] = (bhalf)w.w;
            *(bhalf4*)(lsB + lo) = ow;
        }
        __syncthreads();
        bhalf8 af[4], bf[4];
#pragma unroll
        for (int x = 0; x < 4; ++x) {
            af[x] = *(const bhalf8*)(lsA + sw_off(wm + x * 16 + rsel, quad));
            bf[x] = *(const bhalf8*)(lsB + sw_off(wn + x * 16 + rsel, quad));
        }
#pragma unroll
        for (int mt = 0; mt < 4; ++mt)
#pragma unroll
            for (int nt = 0; nt < 4; ++nt)
                acc[mt][nt] = __builtin_amdgcn_mfma_f32_16x16x32_bf16(af[mt], bf[nt],
                                                                      acc[mt][nt], 0, 0, 0);
        __syncthreads();
    }
#pragma unroll
    for (int mt = 0; mt < 4; ++mt) {
        const int kbase = m0 + wm + mt * 16 + quad * 4;
        const float s0 = rsc[kbase + 0], s1 = rsc[kbase + 1];
        const float s2 = rsc[kbase + 2], s3 = rsc[kbase + 3];
#pragma unroll
        for (int nt = 0; nt < 4; ++nt) {
            const int n = n0 + wn + nt * 16 + rsel;
            const float bn = bias[n];
            bhalf4 o;
            o[0] = (bhalf)(fmaxf(acc[mt][nt][0] + bn, 0.f) * s0);
            o[1] = (bhalf)(fmaxf(acc[mt][nt][1] + bn, 0.f) * s1);
            o[2] = (bhalf)(fmaxf(acc[mt][nt][2] + bn, 0.f) * s2);
            o[3] = (bhalf)(fmaxf(acc[mt][nt][3] + bn, 0.f) * s3);
            *(bhalf4*)(ht + (size_t)n * NN + kbase) = o;
        }
    }
}

// ---------------------------------------------------------------------------
// Pass 4 (fast path): out += rsr[i] * (A16_tile @ ht_tile).
// Block = 512 thr / 8 waves (2m x 4n), tile 128(m) x 256(n), BK=32, K-split 4.
// Staging: 3 global_load_lds(16B) per wave per iter, lane-permuted so LDS
// lands in sw_off swizzle (async + zero bank conflicts). grid (2,64,4)=512
// blocks -> 2 blocks/CU. A re-read only 2x (n-pair dispatch-adjacent -> LLC).
// ---------------------------------------------------------------------------
__global__ __launch_bounds__(512, 4) void k_gemm2_bf(const bhalf* __restrict__ A16,
                                                     const bhalf* __restrict__ ht,
                                                     const float* __restrict__ rsr,
                                                     const int* __restrict__ flag,
                                                     float* __restrict__ out) {
    __shared__ __align__(16) bhalf lsA[128 * 32];  // 8 KB
    __shared__ __align__(16) bhalf lsB[256 * 32];  // 16 KB
    const int n0   = blockIdx.x * 256;
    const int m0   = blockIdx.y * 128;
    const int K0   = blockIdx.z * (NN / 4);
    const int t    = threadIdx.x;
    const int lane = t & 63, wave = t >> 6;  // 8 waves
    const int wm = (wave >> 2) * 64, wn = (wave & 3) * 64;
    const int quad = lane >> 4, rsel = lane & 15;

    // lane-permuted global source for swizzle-compatible GLL16 staging
    const int x   = (lane & 7) ^ ((lane >> 3) & 7);
    const int rin = 2 * (lane >> 3) + (x >> 2);  // row-in-chunk 0..15
    const int seg = x & 3;
    const bhalf* g0 = A16 + (size_t)(m0 + wave * 16 + rin) * NN + K0 + seg * 8;
    const bhalf* g1 = ht + (size_t)(n0 + wave * 16 + rin) * NN + K0 + seg * 8;
    const bhalf* g2 = ht + (size_t)(n0 + 128 + wave * 16 + rin) * NN + K0 + seg * 8;
    bhalf* const l0 = lsA + wave * 512;
    bhalf* const l1 = lsB + wave * 512;
    bhalf* const l2 = lsB + (wave + 8) * 512;

    f32x4 acc[4][4];
#pragma unroll
    for (int a = 0; a < 4; ++a)
#pragma unroll
        for (int bq = 0; bq < 4; ++bq)
#pragma unroll
            for (int e = 0; e < 4; ++e) acc[a][bq][e] = 0.f;

    for (int it = 0; it < (NN / 4) / 32; ++it) {
        GLL16(g0, l0);
        GLL16(g1, l1);
        GLL16(g2, l2);
        g0 += 32; g1 += 32; g2 += 32;
        __syncthreads();  // drains vmcnt (compiler-inserted) -> staging visible
        bhalf8 af[4], bf[4];
#pragma unroll
        for (int i = 0; i < 4; ++i) {
            af[i] = *(const bhalf8*)(lsA + sw_off(wm + i * 16 + rsel, quad));
            bf[i] = *(const bhalf8*)(lsB + sw_off(wn + i * 16 + rsel, quad));
        }
#pragma unroll
        for (int mt = 0; mt < 4; ++mt)
#pragma unroll
            for (int nt = 0; nt < 4; ++nt)
                acc[mt][nt] = __builtin_amdgcn_mfma_f32_16x16x32_bf16(af[mt], bf[nt],
                                                                      acc[mt][nt], 0, 0, 0);
        __syncthreads();
    }
    const int fl = *flag;
    if (fl) return;  // out already = feat
#pragma unroll
    for (int mt = 0; mt < 4; ++mt) {
        const int ibase = m0 + wm + mt * 16 + quad * 4;
#pragma unroll
        for (int rg = 0; rg < 4; ++rg) {
            const int i   = ibase + rg;
            const float s = rsr[i];
#pragma unroll
            for (int nt = 0; nt < 4; ++nt) {
                const int j = n0 + wn + nt * 16 + rsel;
                atomicAdd(&out[(size_t)i * CC + j], s * acc[mt][nt][rg]);
            }
        }
    }
}

// ---------------------------------------------------------------------------
// Pass 4 (fallback, no bf16 ws): round-3 structure with fp32->bf16 convert.
// ---------------------------------------------------------------------------
__global__ __launch_bounds__(256, 3) void k_gemm2_f32(const float* __restrict__ A32,
                                                      const bhalf* __restrict__ ht,
                                                      const float* __restrict__ rsr,
                                                      const int* __restrict__ flag,
                                                      float* __restrict__ out) {
    __shared__ __align__(16) bhalf lsA[128 * 32];
    __shared__ __align__(16) bhalf lsB[128 * 32];
    const int n0   = blockIdx.x * 128;
    const int m0   = blockIdx.y * 128;
    const int K0   = blockIdx.z * (NN / 4);
    const int t    = threadIdx.x;
    const int lane = t & 63, wave = t >> 6;
    const int wm = (wave >> 1) * 64, wn = (wave & 1) * 64;
    const int quad = lane >> 4, rsel = lane & 15;
    f32x4 acc[4][4];
#pragma unroll
    for (int a = 0; a < 4; ++a)
#pragma unroll
        for (int bq = 0; bq < 4; ++bq)
#pragma unroll
            for (int e = 0; e < 4; ++e) acc[a][bq][e] = 0.f;

    for (int k0 = K0; k0 < K0 + NN / 4; k0 += 32) {
#pragma unroll
        for (int i = 0; i < 4; ++i) {
            const int ch = i * 256 + t;
            const int r = ch >> 3, s8 = ch & 7;
            const float4 v = *(const float4*)(A32 + (size_t)(m0 + r) * NN + k0 + s8 * 4);
            bhalf4 o;
            o[0] = (bhalf)v.x; o[1] = (bhalf)v.y; o[2] = (bhalf)v.z; o[3] = (bhalf)v.w;
            *(bhalf4*)(lsA + sw_off(r, s8 >> 1) + (s8 & 1) * 4) = o;
        }
#pragma unroll
        for (int i = 0; i < 2; ++i) {
            const int ch = i * 256 + t;
            const int r = ch >> 2, seg = ch & 3;
            const bhalf8 v = *(const bhalf8*)(ht + (size_t)(n0 + r) * NN + k0 + seg * 8);
            *(bhalf8*)(lsB + sw_off(r, seg)) = v;
        }
        __syncthreads();
        bhalf8 af[4], bf[4];
#pragma unroll
        for (int i = 0; i < 4; ++i) {
            af[i] = *(const bhalf8*)(lsA + sw_off(wm + i * 16 + rsel, quad));
            bf[i] = *(const bhalf8*)(lsB + sw_off(wn + i * 16 + rsel, quad));
        }
#pragma unroll
        for (int mt = 0; mt < 4; ++mt)
#pragma unroll
            for (int nt = 0; nt < 4; ++nt)
                acc[mt][nt] = __builtin_amdgcn_mfma_f32_16x16x32_bf16(af[mt], bf[nt],
                                                                      acc[mt][nt], 0, 0, 0);
        __syncthreads();
    }
    const int fl = *flag;
    if (fl) return;
#pragma unroll
    for (int mt = 0; mt < 4; ++mt) {
        const int ibase = m0 + wm + mt * 16 + quad * 4;
#pragma unroll
        for (int rg = 0; rg < 4; ++rg) {
            const int i   = ibase + rg;
            const float s = rsr[i];
#pragma unroll
            for (int nt = 0; nt < 4; ++nt) {
                const int j = n0 + wn + nt * 16 + rsel;
                atomicAdd(&out[(size_t)i * CC + j], s * acc[mt][nt][rg]);
            }
        }
    }
}

// ---------------------------------------------------------------------------
// Workspace layout:
//   0        row_deg  f32[8192]
//   32768    col_deg  f32[8192]
//   65536    rsqrt_row f32[8192]
//   98304    rsqrt_col f32[8192]
//   131072   flag int
//   262144   ht bf16[512*8192]        (8 MB)
//   16777216 A_bf16 bf16[8192*8192]   (128 MB, only if ws_size allows)
// ---------------------------------------------------------------------------
extern "C" void kernel_launch(void* const* d_in, const int* in_sizes, int n_in,
                              void* d_out, int out_size, void* d_ws, size_t ws_size,
                              hipStream_t stream) {
    const float* feat = (const float*)d_in[0];
    const float* adj  = (const float*)d_in[1];
    const float* W    = (const float*)d_in[2];
    const float* bias = (const float*)d_in[3];
    float* out = (float*)d_out;

    char* ws       = (char*)d_ws;
    float* row_deg = (float*)(ws);
    float* col_deg = (float*)(ws + 32768);
    float* rsr     = (float*)(ws + 65536);
    float* rsc     = (float*)(ws + 98304);
    int* flag      = (int*)(ws + 131072);
    bhalf* ht      = (bhalf*)(ws + 262144);
    bhalf* Abf     = (bhalf*)(ws + 16777216);

    const bool use_bf16 =
        ws_size >= (size_t)16777216 + (size_t)NN * (size_t)NN * 2;

    hipMemsetAsync(d_ws, 0, 131072 + 64, stream);
    // out = identity (feat); gemm2 atomically accumulates on top
    k_copy<<<NN * CC / 4 / 256, 256, 0, stream>>>((const float4*)feat, (float4*)out);

    if (use_bf16)
        k_degrees<1><<<dim3(8, 256), 256, 0, stream>>>(adj, row_deg, col_deg, Abf);
    else
        k_degrees<0><<<dim3(8, 256), 256, 0, stream>>>(adj, row_deg, col_deg, nullptr);

    k_finalize<<<32, 256, 0, stream>>>(row_deg, col_deg, rsr, rsc, flag);

    k_h<<<dim3(4, 64), 256, 0, stream>>>(feat, W, bias, rsc, ht);

    if (use_bf16)
        k_gemm2_bf<<<dim3(2, 64, 4), 512, 0, stream>>>(Abf, ht, rsr, flag, out);
    else
        k_gemm2_f32<<<dim3(4, 64, 4), 256, 0, stream>>>(adj, ht, rsr, flag, out);
}